// Round 16
// baseline (305.961 us; speedup 1.0000x reference)
//
#include <hip/hip_runtime.h>
#include <math.h>

#define NN 50000
#define NE 800000
#define HD 128
#define NL 3
#define NG 64
#define BN_EPS 1e-5f
#define NB 196   // dst buckets of 256 nodes
#define EPB 4096 // edges per block in bucket passes
#define NCNT ((NE + EPB - 1) / EPB)     // 196 histogram blocks
#define MAXB 8192
#define WSTR 136 // LDS weight row stride (fp16 elems)
#define NREP 32  // stats replicas (TCC same-address contention /32)
#define GATHB ((NN * 16 + 255) / 256)   // 3125 gather blocks

typedef _Float16 f16;
typedef __attribute__((ext_vector_type(8))) _Float16 f16x8;
typedef __attribute__((ext_vector_type(4))) float f32x4;

// ================= CSR build: bucketed counting sort =================
// kept as its own 196-block launch: short critical path into buckscan
// (R15's fusion with cvt put 25.6MB of cvt reads on the CSR chain: +7us)
__global__ __launch_bounds__(256)
void buckcnt_kernel(const int* __restrict__ dst, int* __restrict__ bcnt) {
    __shared__ int h[NB];
    for (int i = threadIdx.x; i < NB; i += 256) h[i] = 0;
    __syncthreads();
    int base = blockIdx.x * EPB;
#pragma unroll
    for (int it = 0; it < EPB / 256; ++it) {
        int e = base + it * 256 + threadIdx.x;
        if (e < NE) atomicAdd(&h[dst[e] >> 8], 1);
    }
    __syncthreads();
    for (int i = threadIdx.x; i < NB; i += 256)
        if (h[i]) atomicAdd(&bcnt[i], h[i]);
}

__global__ void buckscan_kernel(const int* __restrict__ bcnt, int* __restrict__ bbase,
                                int* __restrict__ bcur) {
    __shared__ int sh[256];
    int tid = threadIdx.x;
    int v = (tid < NB) ? bcnt[tid] : 0;
    sh[tid] = v;
    __syncthreads();
    for (int off = 1; off < 256; off <<= 1) {
        int t = (tid >= off) ? sh[tid - off] : 0;
        __syncthreads();
        sh[tid] += t;
        __syncthreads();
    }
    int excl = sh[tid] - v;
    if (tid < NB) { bbase[tid] = excl; bcur[tid] = excl; }
    if (tid == NB - 1) bbase[NB] = excl + v;  // == NE
}

__global__ __launch_bounds__(256)
void buckscat_kernel(const int* __restrict__ src, const int* __restrict__ dst,
                     int* __restrict__ bcur, unsigned* __restrict__ staging) {
    __shared__ int h[NB];
    __shared__ int rbase[NB];
    for (int i = threadIdx.x; i < NB; i += 256) h[i] = 0;
    __syncthreads();
    int base = blockIdx.x * EPB;
#pragma unroll
    for (int it = 0; it < EPB / 256; ++it) {
        int e = base + it * 256 + threadIdx.x;
        if (e < NE) atomicAdd(&h[dst[e] >> 8], 1);
    }
    __syncthreads();
    for (int i = threadIdx.x; i < NB; i += 256) {
        rbase[i] = h[i] ? atomicAdd(&bcur[i], h[i]) : 0;
        h[i] = 0;
    }
    __syncthreads();
#pragma unroll
    for (int it = 0; it < EPB / 256; ++it) {
        int e = base + it * 256 + threadIdx.x;
        if (e < NE) {
            int d = dst[e];
            int k = d >> 8;
            int p = rbase[k] + atomicAdd(&h[k], 1);
            staging[p] = ((unsigned)d << 16) | (unsigned)src[e];
        }
    }
}

// phase 3 + degree histogram (histd folded in)
__global__ __launch_bounds__(256)
void buckbuild_kernel(const unsigned* __restrict__ staging, const int* __restrict__ bbase,
                      int* __restrict__ rowptr, int* __restrict__ perm,
                      int* __restrict__ dhist) {
    __shared__ int cnt[256];
    __shared__ int pre[256];
    __shared__ int hh[256];
    __shared__ unsigned short lperm[MAXB];
    const int k = blockIdx.x;
    const int s = bbase[k], e = bbase[k + 1];
    const int size = e - s;
    const int tid = threadIdx.x;
    cnt[tid] = 0;
    hh[tid] = 0;
    __syncthreads();
    for (int i = s + tid; i < e; i += 256)
        atomicAdd(&cnt[(int)(staging[i] >> 16) - k * 256], 1);
    __syncthreads();
    int v = cnt[tid];
    pre[tid] = v;
    __syncthreads();
    for (int off = 1; off < 256; off <<= 1) {
        int t = (tid >= off) ? pre[tid - off] : 0;
        __syncthreads();
        pre[tid] += t;
        __syncthreads();
    }
    int excl = pre[tid] - v;
    int n = k * 256 + tid;
    if (n < NN) {
        rowptr[n] = s + excl;
        atomicAdd(&hh[v > 255 ? 255 : v], 1);
    }
    if (n == NN - 1) rowptr[NN] = NE;
    cnt[tid] = excl;  // reuse as scatter cursors
    __syncthreads();
    if (hh[tid]) atomicAdd(&dhist[tid], hh[tid]);
    if (size <= MAXB) {
        for (int i = s + tid; i < e; i += 256) {
            unsigned w = staging[i];
            int dl = (int)(w >> 16) - k * 256;
            int p = atomicAdd(&cnt[dl], 1);
            lperm[p] = (unsigned short)(w & 0xffffu);
        }
        __syncthreads();
        for (int i = tid; i < size; i += 256) perm[s + i] = (int)lperm[i];
    } else {
        for (int i = s + tid; i < e; i += 256) {
            unsigned w = staging[i];
            int dl = (int)(w >> 16) - k * 256;
            int p = atomicAdd(&cnt[dl], 1);
            perm[s + p] = (int)(w & 0xffffu);
        }
    }
}

__global__ void dscan_kernel(const int* __restrict__ dhist, int* __restrict__ dcur) {
    __shared__ int sh[256];
    int tid = threadIdx.x;
    int v = dhist[tid];
    sh[tid] = v;
    __syncthreads();
    for (int off = 1; off < 256; off <<= 1) {
        int t = (tid >= off) ? sh[tid - off] : 0;
        __syncthreads();
        sh[tid] += t;
        __syncthreads();
    }
    dcur[tid] = sh[tid] - v;  // exclusive
}

// contention-free placement (per-block LDS hist -> run reservation -> scatter)
__global__ __launch_bounds__(256)
void place_kernel(const int* __restrict__ rowptr, int* __restrict__ dcur,
                  int* __restrict__ norder) {
    __shared__ int h[256];
    __shared__ int rbase[256];
    h[threadIdx.x] = 0;
    __syncthreads();
    int n = blockIdx.x * 256 + threadIdx.x;
    int d = -1;
    if (n < NN) {
        d = rowptr[n + 1] - rowptr[n];
        if (d > 255) d = 255;
        atomicAdd(&h[d], 1);
    }
    __syncthreads();
    rbase[threadIdx.x] = h[threadIdx.x] ? atomicAdd(&dcur[threadIdx.x], h[threadIdx.x]) : 0;
    h[threadIdx.x] = 0;
    __syncthreads();
    if (n < NN) {
        int p = rbase[d] + atomicAdd(&h[d], 1);
        norder[p] = n;
    }
}

// ================= cvt + bounds (off the CSR critical path) =================
__global__ void cvt_kernel(const float* __restrict__ x, f16* __restrict__ hf,
                           const int* __restrict__ batch, int* __restrict__ gb) {
    int nb = blockIdx.x * 256 + threadIdx.x;
    if (nb < NN) {
        int b = batch[nb];
        int bp = (nb == 0) ? -1 : batch[nb - 1];
        for (int g = bp + 1; g <= b; ++g) gb[g] = nb;
        if (nb == NN - 1)
            for (int g = b + 1; g <= NG; ++g) gb[g] = NN;
    }
    int t = blockIdx.x * 256 + threadIdx.x;
    if (t >= NN * 16) return;
    int n = t >> 4, q = t & 15;
    float4 v0 = ((const float4*)x)[n * 32 + q * 2];
    float4 v1 = ((const float4*)x)[n * 32 + q * 2 + 1];
    f16x8 o;
    o[0] = (f16)v0.x; o[1] = (f16)v0.y; o[2] = (f16)v0.z; o[3] = (f16)v0.w;
    o[4] = (f16)v1.x; o[5] = (f16)v1.y; o[6] = (f16)v1.z; o[7] = (f16)v1.w;
    *(f16x8*)(hf + (size_t)n * HD + q * 8) = o;
}

// BN affine from replicated raw sums
__device__ __forceinline__ void bn_affine(const float* __restrict__ sR, int c,
                                          const float* __restrict__ gam,
                                          const float* __restrict__ bet,
                                          float* sc, float* sh) {
    float s0 = 0.f, s1 = 0.f;
#pragma unroll 8
    for (int r = 0; r < NREP; ++r) {
        s0 += sR[r * 256 + c];
        s1 += sR[r * 256 + 128 + c];
    }
    float invN = 1.0f / (float)NN;
    float mu = s0 * invN;
    float var = s1 * invN - mu * mu;
    var = var < 0.f ? 0.f : var;
    float s = rsqrtf(var + BN_EPS) * gam[c];
    *sc = s;
    *sh = bet[c] - mu * s;
}

// ============ fused gather + weight-prep launch ============
__global__ __launch_bounds__(256)
void gatherw_kernel(const f16* __restrict__ hf, const int* __restrict__ rowptr,
                    const int* __restrict__ perm, const int* __restrict__ norder,
                    const float* __restrict__ statsPrev,  // null for layer 0
                    const float* __restrict__ gamP, const float* __restrict__ betP,
                    const float* __restrict__ Wl, const float* __restrict__ Wr,
                    const float* __restrict__ bl,
                    f16* __restrict__ Wh, float* __restrict__ bias2,
                    f16* __restrict__ aggf) {
    __shared__ float red[256];
    if (blockIdx.x >= GATHB) {
        int j = blockIdx.x - GATHB;   // output channel
        int k = threadIdx.x;          // contraction index
        float scp = 1.0f, shp = 0.0f;
        if (statsPrev) bn_affine(statsPrev, k & 127, gamP, betP, &scp, &shp);
        float w = (k < HD) ? Wl[j * HD + k] : Wr[j * HD + (k - HD)];
        Wh[j * 256 + k] = (f16)(w * scp);
        red[k] = shp * w;
        __syncthreads();
        for (int s = 128; s > 0; s >>= 1) {
            if (k < s) red[k] += red[k + s];
            __syncthreads();
        }
        if (k == 0) bias2[j] = bl[j] + red[0];
        return;
    }
    // ---- gather block (degree-sorted order) ----
    int t = blockIdx.x * 256 + threadIdx.x;
    int i = t >> 4, q = t & 15;
    if (i >= NN) return;
    int n = norder[i];
    int r0 = rowptr[n], r1 = rowptr[n + 1];
    float sA[8] = {0.f, 0.f, 0.f, 0.f, 0.f, 0.f, 0.f, 0.f};
    float sB[8] = {0.f, 0.f, 0.f, 0.f, 0.f, 0.f, 0.f, 0.f};
    int e = r0;
    for (; e + 8 <= r1; e += 8) {
        int i0 = perm[e], i1 = perm[e + 1], i2 = perm[e + 2], i3 = perm[e + 3];
        int i4 = perm[e + 4], i5 = perm[e + 5], i6 = perm[e + 6], i7 = perm[e + 7];
        f16x8 v0 = *(const f16x8*)(hf + (size_t)i0 * HD + q * 8);
        f16x8 v1 = *(const f16x8*)(hf + (size_t)i1 * HD + q * 8);
        f16x8 v2 = *(const f16x8*)(hf + (size_t)i2 * HD + q * 8);
        f16x8 v3 = *(const f16x8*)(hf + (size_t)i3 * HD + q * 8);
        f16x8 v4 = *(const f16x8*)(hf + (size_t)i4 * HD + q * 8);
        f16x8 v5 = *(const f16x8*)(hf + (size_t)i5 * HD + q * 8);
        f16x8 v6 = *(const f16x8*)(hf + (size_t)i6 * HD + q * 8);
        f16x8 v7 = *(const f16x8*)(hf + (size_t)i7 * HD + q * 8);
#pragma unroll
        for (int j = 0; j < 8; ++j) {
            sA[j] += ((float)v0[j] + (float)v2[j]) + ((float)v4[j] + (float)v6[j]);
            sB[j] += ((float)v1[j] + (float)v3[j]) + ((float)v5[j] + (float)v7[j]);
        }
    }
    for (; e + 2 <= r1; e += 2) {
        int i0 = perm[e], i1 = perm[e + 1];
        f16x8 v0 = *(const f16x8*)(hf + (size_t)i0 * HD + q * 8);
        f16x8 v1 = *(const f16x8*)(hf + (size_t)i1 * HD + q * 8);
#pragma unroll
        for (int j = 0; j < 8; ++j) { sA[j] += (float)v0[j]; sB[j] += (float)v1[j]; }
    }
    if (e < r1) {
        int i0 = perm[e];
        f16x8 v0 = *(const f16x8*)(hf + (size_t)i0 * HD + q * 8);
#pragma unroll
        for (int j = 0; j < 8; ++j) sA[j] += (float)v0[j];
    }
    float s[8];
#pragma unroll
    for (int j = 0; j < 8; ++j) s[j] = sA[j] + sB[j];
    if (r1 > r0) {
        float r = 1.0f / (float)(r1 - r0);
#pragma unroll
        for (int j = 0; j < 8; ++j) s[j] *= r;
    } else if (statsPrev) {
        // deg-0 sentinel: -sh/sc so the BN-folded GEMM contribution is exactly 0
#pragma unroll
        for (int j = 0; j < 8; ++j) {
            float sc, sh;
            bn_affine(statsPrev, q * 8 + j, gamP, betP, &sc, &sh);
            s[j] = (sc != 0.f) ? (-sh / sc) : 0.f;
        }
    }  // layer 0: sentinel is 0 (identity affine), s[] already 0
    f16x8 o;
#pragma unroll
    for (int j = 0; j < 8; ++j) o[j] = (f16)s[j];
    *(f16x8*)(aggf + (size_t)n * HD + q * 8) = o;
}

// ---------------- fp16 MFMA GEMM, B staged in LDS, A hoisted, NREP stats ----------------
__global__ __launch_bounds__(256, 4)
void mfma_gemm(const f16* __restrict__ aggf, const f16* __restrict__ hf,
               const f16* __restrict__ Wh, const float* __restrict__ bias2,
               f16* __restrict__ yout, float* __restrict__ statsN) {
    __shared__ f16 wls[128 * WSTR];   // 34816 B; aliased as f32 ls[64][132] in epilogue
    __shared__ float st[256];
    float* ls = (float*)wls;
    const int tid = threadIdx.x;
    st[tid] = 0.0f;
    const int wave = tid >> 6, lane = tid & 63;
    const int lm = lane & 15, quad = lane >> 4;
    const int m0 = blockIdx.x * 64 + wave * 16;
    int ar = m0 + lm;
    if (ar >= NN) ar = NN - 1;

    f16x8 a[8];
#pragma unroll
    for (int c = 0; c < 4; ++c)
        a[c] = *(const f16x8*)(aggf + (size_t)ar * HD + c * 32 + quad * 8);
#pragma unroll
    for (int c = 0; c < 4; ++c)
        a[4 + c] = *(const f16x8*)(hf + (size_t)ar * HD + c * 32 + quad * 8);

    f32x4 acc[8];
#pragma unroll
    for (int t = 0; t < 8; ++t) acc[t] = (f32x4){0.f, 0.f, 0.f, 0.f};

#pragma unroll
    for (int half = 0; half < 2; ++half) {
        __syncthreads();
#pragma unroll
        for (int it = 0; it < 8; ++it) {
            int slot = tid + it * 256;
            int r = slot >> 4, c = slot & 15;
            *(f16x8*)&wls[r * WSTR + c * 8] =
                *(const f16x8*)(Wh + (size_t)r * 256 + half * 128 + c * 8);
        }
        __syncthreads();
#pragma unroll
        for (int c = 0; c < 4; ++c) {
#pragma unroll
            for (int t = 0; t < 8; ++t) {
                f16x8 b = *(const f16x8*)&wls[(t * 16 + lm) * WSTR + c * 32 + quad * 8];
                acc[t] = __builtin_amdgcn_mfma_f32_16x16x32_f16(a[half * 4 + c], b, acc[t], 0, 0, 0);
            }
        }
    }
    __syncthreads();

#pragma unroll
    for (int t = 0; t < 8; ++t) {
        int n = t * 16 + lm;
        float bs = bias2[n];
        float s = 0.f, sq = 0.f;
#pragma unroll
        for (int r = 0; r < 4; ++r) {
            int gr = m0 + quad * 4 + r;
            float y = fmaxf(acc[t][r] + bs, 0.f);
            if (gr >= NN) y = 0.f;
            ls[(wave * 16 + quad * 4 + r) * 132 + n] = y;
            s += y; sq += y * y;
        }
        s += __shfl_xor(s, 16); s += __shfl_xor(s, 32);
        sq += __shfl_xor(sq, 16); sq += __shfl_xor(sq, 32);
        if (quad == 0) { atomicAdd(&st[n], s); atomicAdd(&st[128 + n], sq); }
    }
    __syncthreads();
    atomicAdd(&statsN[(blockIdx.x & (NREP - 1)) * 256 + tid], st[tid]);

#pragma unroll
    for (int it = 0; it < 4; ++it) {
        int slot = tid + it * 256;
        int r = slot >> 4, c = slot & 15;
        int g = blockIdx.x * 64 + r;
        if (g < NN) {
            const float* p = &ls[r * 132 + c * 8];
            f16x8 o;
#pragma unroll
            for (int j = 0; j < 8; ++j) o[j] = (f16)p[j];
            *(f16x8*)(yout + (size_t)g * HD + c * 8) = o;
        }
    }
}

// ============ fused pool+head via linearity through affine BN ============
__global__ __launch_bounds__(256)
void poolhead_kernel(const f16* __restrict__ hf, const int* __restrict__ gb,
                     const float* __restrict__ stats3, const float* __restrict__ gam3,
                     const float* __restrict__ bet3, const float* __restrict__ fcw,
                     const float* __restrict__ fcb, float* __restrict__ out) {
    __shared__ float scs[128], shs[128];
    __shared__ float red[256];
    const int tid = threadIdx.x;
    if (tid < 128) bn_affine(stats3, tid, gam3, bet3, &scs[tid], &shs[tid]);
    __syncthreads();
    int g = blockIdx.x;
    int s = gb[g], e = gb[g + 1];
    int q = tid & 15, r = tid >> 4;
    float sum[8] = {0.f, 0.f, 0.f, 0.f, 0.f, 0.f, 0.f, 0.f};
    for (int n = s + r; n < e; n += 16) {
        f16x8 v = *(const f16x8*)(hf + (size_t)n * HD + q * 8);
#pragma unroll
        for (int j = 0; j < 8; ++j) sum[j] += (float)v[j];
    }
    float part = 0.f;
#pragma unroll
    for (int j = 0; j < 8; ++j) {
        int c = q * 8 + j;
        part += sum[j] * scs[c] * fcw[c];
    }
    if (r == 0) {
        float cnt = (float)(e - s);
#pragma unroll
        for (int j = 0; j < 8; ++j) {
            int c = q * 8 + j;
            part += cnt * shs[c] * fcw[c];
        }
    }
    red[tid] = part;
    __syncthreads();
    for (int st = 128; st > 0; st >>= 1) {
        if (tid < st) red[tid] += red[tid + st];
        __syncthreads();
    }
    if (tid == 0) out[g] = 1.0f / (1.0f + expf(-(red[0] + fcb[0])));
}

extern "C" void kernel_launch(void* const* d_in, const int* in_sizes, int n_in,
                              void* d_out, int out_size, void* d_ws, size_t ws_size,
                              hipStream_t stream) {
    const float* x     = (const float*)d_in[0];
    const int*   ei    = (const int*)d_in[1];
    const int*   src   = ei;
    const int*   dst   = ei + NE;
    const int*   batch = (const int*)d_in[3];
    const float* Wl    = (const float*)d_in[4];
    const float* bl    = (const float*)d_in[5];
    const float* Wr    = (const float*)d_in[6];
    const float* gamma = (const float*)d_in[7];
    const float* beta  = (const float*)d_in[8];
    const float* fcw   = (const float*)d_in[9];
    const float* fcb   = (const float*)d_in[10];
    float* out = (float*)d_out;

    f16* hf0  = (f16*)d_ws;                       // [NN][128] fp16 (x converted)
    f16* hfA  = hf0 + (size_t)NN * HD;
    f16* hfB  = hfA + (size_t)NN * HD;
    f16* aggf = hfB + (size_t)NN * HD;
    f16* Wh   = aggf + (size_t)NN * HD;           // [128][256] fp16
    float* bias2 = (float*)(Wh + 128 * 256);      // 128
    // ---- contiguous zero zone (single memset) ----
    float* zero0    = bias2 + HD;
    float* statsRaw = zero0;                      // 3 layers x NREP x 256
    int* bcnt  = (int*)(statsRaw + 3 * NREP * 256);  // NB
    int* dhist = bcnt + NB;                       // 256
    size_t zero_bytes = (3 * NREP * 256) * sizeof(float) + (NB + 256) * sizeof(int);
    // ---- rest ----
    int* rowptr  = dhist + 256;                   // NN+1
    int* perm    = rowptr + NN + 1;               // NE
    unsigned* staging = (unsigned*)(perm + NE);   // NE
    int* bbase   = (int*)(staging + NE);          // NB+1
    int* bcur    = bbase + NB + 1;                // NB
    int* gb      = bcur + NB;                     // NG+1
    int* norder  = gb + NG + 1;                   // NN
    int* dcur    = norder + NN;                   // 256

    hipMemsetAsync(zero0, 0, zero_bytes, stream);

    buckcnt_kernel<<<NCNT, 256, 0, stream>>>(dst, bcnt);
    buckscan_kernel<<<1, 256, 0, stream>>>(bcnt, bbase, bcur);
    buckscat_kernel<<<NCNT, 256, 0, stream>>>(src, dst, bcur, staging);
    buckbuild_kernel<<<NB, 256, 0, stream>>>(staging, bbase, rowptr, perm, dhist);
    dscan_kernel<<<1, 256, 0, stream>>>(dhist, dcur);
    place_kernel<<<(NN + 255) / 256, 256, 0, stream>>>(rowptr, dcur, norder);
    cvt_kernel<<<GATHB, 256, 0, stream>>>(x, hf0, batch, gb);

    const f16* hin = hf0;
    f16* houts[3] = {hfA, hfB, hfA};
    for (int l = 0; l < NL; ++l) {
        const float* stP = (l == 0) ? nullptr : (statsRaw + (l - 1) * NREP * 256);
        const float* gP  = gamma + (l == 0 ? 0 : (l - 1)) * HD;
        const float* bP  = beta + (l == 0 ? 0 : (l - 1)) * HD;
        gatherw_kernel<<<GATHB + 128, 256, 0, stream>>>(
            hin, rowptr, perm, norder, stP, gP, bP,
            Wl + l * HD * HD, Wr + l * HD * HD, bl + l * HD, Wh, bias2, aggf);
        mfma_gemm<<<(NN + 63) / 64, 256, 0, stream>>>(aggf, hin, Wh, bias2,
                                                      houts[l], statsRaw + l * NREP * 256);
        hin = houts[l];
    }
    poolhead_kernel<<<NG, 256, 0, stream>>>(hfA, gb, statsRaw + 2 * NREP * 256,
                                            gamma + 2 * HD, beta + 2 * HD, fcw, fcb, out);
}

// Round 17
// 298.054 us; speedup vs baseline: 1.0265x; 1.0265x over previous
//
#include <hip/hip_runtime.h>
#include <math.h>

#define NN 50000
#define NE 800000
#define HD 128
#define NL 3
#define NG 64
#define BN_EPS 1e-5f
#define NB 196   // dst buckets of 256 nodes
#define EPB 4096 // edges per block in bucket passes
#define NCNT ((NE + EPB - 1) / EPB)     // 196 histogram blocks
#define MAXB 8192
#define WSTR 136 // LDS weight row stride (fp16 elems)
#define NREP 32  // stats replicas (TCC same-address contention /32)
#define GATHB ((NN * 16 + 255) / 256)   // 3125 gather blocks

typedef _Float16 f16;
typedef __attribute__((ext_vector_type(8))) _Float16 f16x8;
typedef __attribute__((ext_vector_type(4))) float f32x4;

// ================= CSR build: bucketed counting sort =================
__global__ __launch_bounds__(256)
void buckcnt_kernel(const int* __restrict__ dst, int* __restrict__ bcnt) {
    __shared__ int h[NB];
    for (int i = threadIdx.x; i < NB; i += 256) h[i] = 0;
    __syncthreads();
    int base = blockIdx.x * EPB;
#pragma unroll
    for (int it = 0; it < EPB / 256; ++it) {
        int e = base + it * 256 + threadIdx.x;
        if (e < NE) atomicAdd(&h[dst[e] >> 8], 1);
    }
    __syncthreads();
    for (int i = threadIdx.x; i < NB; i += 256)
        if (h[i]) atomicAdd(&bcnt[i], h[i]);
}

__global__ void buckscan_kernel(const int* __restrict__ bcnt, int* __restrict__ bbase,
                                int* __restrict__ bcur) {
    __shared__ int sh[256];
    int tid = threadIdx.x;
    int v = (tid < NB) ? bcnt[tid] : 0;
    sh[tid] = v;
    __syncthreads();
    for (int off = 1; off < 256; off <<= 1) {
        int t = (tid >= off) ? sh[tid - off] : 0;
        __syncthreads();
        sh[tid] += t;
        __syncthreads();
    }
    int excl = sh[tid] - v;
    if (tid < NB) { bbase[tid] = excl; bcur[tid] = excl; }
    if (tid == NB - 1) bbase[NB] = excl + v;  // == NE
}

__global__ __launch_bounds__(256)
void buckscat_kernel(const int* __restrict__ src, const int* __restrict__ dst,
                     int* __restrict__ bcur, unsigned* __restrict__ staging) {
    __shared__ int h[NB];
    __shared__ int rbase[NB];
    for (int i = threadIdx.x; i < NB; i += 256) h[i] = 0;
    __syncthreads();
    int base = blockIdx.x * EPB;
#pragma unroll
    for (int it = 0; it < EPB / 256; ++it) {
        int e = base + it * 256 + threadIdx.x;
        if (e < NE) atomicAdd(&h[dst[e] >> 8], 1);
    }
    __syncthreads();
    for (int i = threadIdx.x; i < NB; i += 256) {
        rbase[i] = h[i] ? atomicAdd(&bcur[i], h[i]) : 0;
        h[i] = 0;
    }
    __syncthreads();
#pragma unroll
    for (int it = 0; it < EPB / 256; ++it) {
        int e = base + it * 256 + threadIdx.x;
        if (e < NE) {
            int d = dst[e];
            int k = d >> 8;
            int p = rbase[k] + atomicAdd(&h[k], 1);
            staging[p] = ((unsigned)d << 16) | (unsigned)src[e];
        }
    }
}

// phase 3 + degree histogram (histd folded in)
__global__ __launch_bounds__(256)
void buckbuild_kernel(const unsigned* __restrict__ staging, const int* __restrict__ bbase,
                      int* __restrict__ rowptr, int* __restrict__ perm,
                      int* __restrict__ dhist) {
    __shared__ int cnt[256];
    __shared__ int pre[256];
    __shared__ int hh[256];
    __shared__ unsigned short lperm[MAXB];
    const int k = blockIdx.x;
    const int s = bbase[k], e = bbase[k + 1];
    const int size = e - s;
    const int tid = threadIdx.x;
    cnt[tid] = 0;
    hh[tid] = 0;
    __syncthreads();
    for (int i = s + tid; i < e; i += 256)
        atomicAdd(&cnt[(int)(staging[i] >> 16) - k * 256], 1);
    __syncthreads();
    int v = cnt[tid];
    pre[tid] = v;
    __syncthreads();
    for (int off = 1; off < 256; off <<= 1) {
        int t = (tid >= off) ? pre[tid - off] : 0;
        __syncthreads();
        pre[tid] += t;
        __syncthreads();
    }
    int excl = pre[tid] - v;
    int n = k * 256 + tid;
    if (n < NN) {
        rowptr[n] = s + excl;
        atomicAdd(&hh[v > 255 ? 255 : v], 1);
    }
    if (n == NN - 1) rowptr[NN] = NE;
    cnt[tid] = excl;  // reuse as scatter cursors
    __syncthreads();
    if (hh[tid]) atomicAdd(&dhist[tid], hh[tid]);
    if (size <= MAXB) {
        for (int i = s + tid; i < e; i += 256) {
            unsigned w = staging[i];
            int dl = (int)(w >> 16) - k * 256;
            int p = atomicAdd(&cnt[dl], 1);
            lperm[p] = (unsigned short)(w & 0xffffu);
        }
        __syncthreads();
        for (int i = tid; i < size; i += 256) perm[s + i] = (int)lperm[i];
    } else {
        for (int i = s + tid; i < e; i += 256) {
            unsigned w = staging[i];
            int dl = (int)(w >> 16) - k * 256;
            int p = atomicAdd(&cnt[dl], 1);
            perm[s + p] = (int)(w & 0xffffu);
        }
    }
}

__global__ void dscan_kernel(const int* __restrict__ dhist, int* __restrict__ dcur) {
    __shared__ int sh[256];
    int tid = threadIdx.x;
    int v = dhist[tid];
    sh[tid] = v;
    __syncthreads();
    for (int off = 1; off < 256; off <<= 1) {
        int t = (tid >= off) ? sh[tid - off] : 0;
        __syncthreads();
        sh[tid] += t;
        __syncthreads();
    }
    dcur[tid] = sh[tid] - v;  // exclusive
}

// contention-free placement (per-block LDS hist -> run reservation -> scatter)
__global__ __launch_bounds__(256)
void place_kernel(const int* __restrict__ rowptr, int* __restrict__ dcur,
                  int* __restrict__ norder) {
    __shared__ int h[256];
    __shared__ int rbase[256];
    h[threadIdx.x] = 0;
    __syncthreads();
    int n = blockIdx.x * 256 + threadIdx.x;
    int d = -1;
    if (n < NN) {
        d = rowptr[n + 1] - rowptr[n];
        if (d > 255) d = 255;
        atomicAdd(&h[d], 1);
    }
    __syncthreads();
    rbase[threadIdx.x] = h[threadIdx.x] ? atomicAdd(&dcur[threadIdx.x], h[threadIdx.x]) : 0;
    h[threadIdx.x] = 0;
    __syncthreads();
    if (n < NN) {
        int p = rbase[d] + atomicAdd(&h[d], 1);
        norder[p] = n;
    }
}

// ================= cvt + bounds (off the CSR critical path) =================
__global__ void cvt_kernel(const float* __restrict__ x, f16* __restrict__ hf,
                           const int* __restrict__ batch, int* __restrict__ gb) {
    int nb = blockIdx.x * 256 + threadIdx.x;
    if (nb < NN) {
        int b = batch[nb];
        int bp = (nb == 0) ? -1 : batch[nb - 1];
        for (int g = bp + 1; g <= b; ++g) gb[g] = nb;
        if (nb == NN - 1)
            for (int g = b + 1; g <= NG; ++g) gb[g] = NN;
    }
    int t = blockIdx.x * 256 + threadIdx.x;
    if (t >= NN * 16) return;
    int n = t >> 4, q = t & 15;
    float4 v0 = ((const float4*)x)[n * 32 + q * 2];
    float4 v1 = ((const float4*)x)[n * 32 + q * 2 + 1];
    f16x8 o;
    o[0] = (f16)v0.x; o[1] = (f16)v0.y; o[2] = (f16)v0.z; o[3] = (f16)v0.w;
    o[4] = (f16)v1.x; o[5] = (f16)v1.y; o[6] = (f16)v1.z; o[7] = (f16)v1.w;
    *(f16x8*)(hf + (size_t)n * HD + q * 8) = o;
}

// BN affine from replicated raw sums
__device__ __forceinline__ void bn_affine(const float* __restrict__ sR, int c,
                                          const float* __restrict__ gam,
                                          const float* __restrict__ bet,
                                          float* sc, float* sh) {
    float s0 = 0.f, s1 = 0.f;
#pragma unroll 8
    for (int r = 0; r < NREP; ++r) {
        s0 += sR[r * 256 + c];
        s1 += sR[r * 256 + 128 + c];
    }
    float invN = 1.0f / (float)NN;
    float mu = s0 * invN;
    float var = s1 * invN - mu * mu;
    var = var < 0.f ? 0.f : var;
    float s = rsqrtf(var + BN_EPS) * gam[c];
    *sc = s;
    *sh = bet[c] - mu * s;
}

// ============ fused gather + weight-prep launch ============
__global__ __launch_bounds__(256)
void gatherw_kernel(const f16* __restrict__ hf, const int* __restrict__ rowptr,
                    const int* __restrict__ perm, const int* __restrict__ norder,
                    const float* __restrict__ statsPrev,  // null for layer 0
                    const float* __restrict__ gamP, const float* __restrict__ betP,
                    const float* __restrict__ Wl, const float* __restrict__ Wr,
                    const float* __restrict__ bl,
                    f16* __restrict__ Wh, float* __restrict__ bias2,
                    f16* __restrict__ aggf) {
    __shared__ float red[256];
    if (blockIdx.x >= GATHB) {
        int j = blockIdx.x - GATHB;   // output channel
        int k = threadIdx.x;          // contraction index
        float scp = 1.0f, shp = 0.0f;
        if (statsPrev) bn_affine(statsPrev, k & 127, gamP, betP, &scp, &shp);
        float w = (k < HD) ? Wl[j * HD + k] : Wr[j * HD + (k - HD)];
        Wh[j * 256 + k] = (f16)(w * scp);
        red[k] = shp * w;
        __syncthreads();
        for (int s = 128; s > 0; s >>= 1) {
            if (k < s) red[k] += red[k + s];
            __syncthreads();
        }
        if (k == 0) bias2[j] = bl[j] + red[0];
        return;
    }
    // ---- gather block (degree-sorted order) ----
    int t = blockIdx.x * 256 + threadIdx.x;
    int i = t >> 4, q = t & 15;
    if (i >= NN) return;
    int n = norder[i];
    int r0 = rowptr[n], r1 = rowptr[n + 1];
    float sA[8] = {0.f, 0.f, 0.f, 0.f, 0.f, 0.f, 0.f, 0.f};
    float sB[8] = {0.f, 0.f, 0.f, 0.f, 0.f, 0.f, 0.f, 0.f};
    int e = r0;
    for (; e + 8 <= r1; e += 8) {
        int i0 = perm[e], i1 = perm[e + 1], i2 = perm[e + 2], i3 = perm[e + 3];
        int i4 = perm[e + 4], i5 = perm[e + 5], i6 = perm[e + 6], i7 = perm[e + 7];
        f16x8 v0 = *(const f16x8*)(hf + (size_t)i0 * HD + q * 8);
        f16x8 v1 = *(const f16x8*)(hf + (size_t)i1 * HD + q * 8);
        f16x8 v2 = *(const f16x8*)(hf + (size_t)i2 * HD + q * 8);
        f16x8 v3 = *(const f16x8*)(hf + (size_t)i3 * HD + q * 8);
        f16x8 v4 = *(const f16x8*)(hf + (size_t)i4 * HD + q * 8);
        f16x8 v5 = *(const f16x8*)(hf + (size_t)i5 * HD + q * 8);
        f16x8 v6 = *(const f16x8*)(hf + (size_t)i6 * HD + q * 8);
        f16x8 v7 = *(const f16x8*)(hf + (size_t)i7 * HD + q * 8);
#pragma unroll
        for (int j = 0; j < 8; ++j) {
            sA[j] += ((float)v0[j] + (float)v2[j]) + ((float)v4[j] + (float)v6[j]);
            sB[j] += ((float)v1[j] + (float)v3[j]) + ((float)v5[j] + (float)v7[j]);
        }
    }
    for (; e + 2 <= r1; e += 2) {
        int i0 = perm[e], i1 = perm[e + 1];
        f16x8 v0 = *(const f16x8*)(hf + (size_t)i0 * HD + q * 8);
        f16x8 v1 = *(const f16x8*)(hf + (size_t)i1 * HD + q * 8);
#pragma unroll
        for (int j = 0; j < 8; ++j) { sA[j] += (float)v0[j]; sB[j] += (float)v1[j]; }
    }
    if (e < r1) {
        int i0 = perm[e];
        f16x8 v0 = *(const f16x8*)(hf + (size_t)i0 * HD + q * 8);
#pragma unroll
        for (int j = 0; j < 8; ++j) sA[j] += (float)v0[j];
    }
    float s[8];
#pragma unroll
    for (int j = 0; j < 8; ++j) s[j] = sA[j] + sB[j];
    if (r1 > r0) {
        float r = 1.0f / (float)(r1 - r0);
#pragma unroll
        for (int j = 0; j < 8; ++j) s[j] *= r;
    } else if (statsPrev) {
        // deg-0 sentinel: -sh/sc so the BN-folded GEMM contribution is exactly 0
#pragma unroll
        for (int j = 0; j < 8; ++j) {
            float sc, sh;
            bn_affine(statsPrev, q * 8 + j, gamP, betP, &sc, &sh);
            s[j] = (sc != 0.f) ? (-sh / sc) : 0.f;
        }
    }  // layer 0: sentinel is 0 (identity affine), s[] already 0
    f16x8 o;
#pragma unroll
    for (int j = 0; j < 8; ++j) o[j] = (f16)s[j];
    *(f16x8*)(aggf + (size_t)n * HD + q * 8) = o;
}

// ---------------- fp16 MFMA GEMM, B staged in LDS, A hoisted, NREP stats ----------------
__global__ __launch_bounds__(256, 4)
void mfma_gemm(const f16* __restrict__ aggf, const f16* __restrict__ hf,
               const f16* __restrict__ Wh, const float* __restrict__ bias2,
               f16* __restrict__ yout, float* __restrict__ statsN) {
    __shared__ f16 wls[128 * WSTR];   // 34816 B; aliased as f32 ls[64][132] in epilogue
    __shared__ float st[256];
    float* ls = (float*)wls;
    const int tid = threadIdx.x;
    st[tid] = 0.0f;
    const int wave = tid >> 6, lane = tid & 63;
    const int lm = lane & 15, quad = lane >> 4;
    const int m0 = blockIdx.x * 64 + wave * 16;
    int ar = m0 + lm;
    if (ar >= NN) ar = NN - 1;

    f16x8 a[8];
#pragma unroll
    for (int c = 0; c < 4; ++c)
        a[c] = *(const f16x8*)(aggf + (size_t)ar * HD + c * 32 + quad * 8);
#pragma unroll
    for (int c = 0; c < 4; ++c)
        a[4 + c] = *(const f16x8*)(hf + (size_t)ar * HD + c * 32 + quad * 8);

    f32x4 acc[8];
#pragma unroll
    for (int t = 0; t < 8; ++t) acc[t] = (f32x4){0.f, 0.f, 0.f, 0.f};

#pragma unroll
    for (int half = 0; half < 2; ++half) {
        __syncthreads();
#pragma unroll
        for (int it = 0; it < 8; ++it) {
            int slot = tid + it * 256;
            int r = slot >> 4, c = slot & 15;
            *(f16x8*)&wls[r * WSTR + c * 8] =
                *(const f16x8*)(Wh + (size_t)r * 256 + half * 128 + c * 8);
        }
        __syncthreads();
#pragma unroll
        for (int c = 0; c < 4; ++c) {
#pragma unroll
            for (int t = 0; t < 8; ++t) {
                f16x8 b = *(const f16x8*)&wls[(t * 16 + lm) * WSTR + c * 32 + quad * 8];
                acc[t] = __builtin_amdgcn_mfma_f32_16x16x32_f16(a[half * 4 + c], b, acc[t], 0, 0, 0);
            }
        }
    }
    __syncthreads();

#pragma unroll
    for (int t = 0; t < 8; ++t) {
        int n = t * 16 + lm;
        float bs = bias2[n];
        float s = 0.f, sq = 0.f;
#pragma unroll
        for (int r = 0; r < 4; ++r) {
            int gr = m0 + quad * 4 + r;
            float y = fmaxf(acc[t][r] + bs, 0.f);
            if (gr >= NN) y = 0.f;
            ls[(wave * 16 + quad * 4 + r) * 132 + n] = y;
            s += y; sq += y * y;
        }
        s += __shfl_xor(s, 16); s += __shfl_xor(s, 32);
        sq += __shfl_xor(sq, 16); sq += __shfl_xor(sq, 32);
        if (quad == 0) { atomicAdd(&st[n], s); atomicAdd(&st[128 + n], sq); }
    }
    __syncthreads();
    atomicAdd(&statsN[(blockIdx.x & (NREP - 1)) * 256 + tid], st[tid]);

#pragma unroll
    for (int it = 0; it < 4; ++it) {
        int slot = tid + it * 256;
        int r = slot >> 4, c = slot & 15;
        int g = blockIdx.x * 64 + r;
        if (g < NN) {
            const float* p = &ls[r * 132 + c * 8];
            f16x8 o;
#pragma unroll
            for (int j = 0; j < 8; ++j) o[j] = (f16)p[j];
            *(f16x8*)(yout + (size_t)g * HD + c * 8) = o;
        }
    }
}

// ---------------- pooling: 8 splits/group (512 blocks; keeps CUs saturated) ----------
__global__ __launch_bounds__(256)
void pool2_kernel(const f16* __restrict__ hf, const int* __restrict__ gb,
                  float* __restrict__ pooled) {
    __shared__ float red[16 * 128];
    int g = blockIdx.x >> 3, sp = blockIdx.x & 7;
    int s = gb[g], e = gb[g + 1];
    int q = threadIdx.x & 15, r = threadIdx.x >> 4;
    float a[8] = {0.f, 0.f, 0.f, 0.f, 0.f, 0.f, 0.f, 0.f};
    for (int n = s + sp * 16 + r; n < e; n += 128) {
        f16x8 v = *(const f16x8*)(hf + (size_t)n * HD + q * 8);
#pragma unroll
        for (int j = 0; j < 8; ++j) a[j] += (float)v[j];
    }
#pragma unroll
    for (int j = 0; j < 8; ++j) red[r * 128 + q * 8 + j] = a[j];
    __syncthreads();
    for (int stp = 8; stp >= 1; stp >>= 1) {
        if (r < stp) {
#pragma unroll
            for (int j = 0; j < 8; ++j)
                red[r * 128 + q * 8 + j] += red[(r + stp) * 128 + q * 8 + j];
        }
        __syncthreads();
    }
    if (r == 0) {
#pragma unroll
        for (int j = 0; j < 8; ++j) atomicAdd(&pooled[g * HD + q * 8 + j], red[q * 8 + j]);
    }
}

// ---------------- head: layer-3 BN (from replicated stats) + dot + sigmoid ----------
__global__ void head_kernel(const float* __restrict__ pooled, const int* __restrict__ gb,
                            const float* __restrict__ stats3, const float* __restrict__ gam3,
                            const float* __restrict__ bet3, const float* __restrict__ fcw,
                            const float* __restrict__ fcb, float* __restrict__ out) {
    __shared__ float red[2];
    int g = blockIdx.x, c = threadIdx.x;  // 128 threads
    float sc, sh;
    bn_affine(stats3, c, gam3, bet3, &sc, &sh);
    float cnt = (float)(gb[g + 1] - gb[g]);
    float v = (pooled[g * HD + c] * sc + cnt * sh) * fcw[c];
#pragma unroll
    for (int o = 32; o > 0; o >>= 1) v += __shfl_xor(v, o);
    if ((c & 63) == 0) red[c >> 6] = v;
    __syncthreads();
    if (c == 0) {
        float s = red[0] + red[1] + fcb[0];
        out[g] = 1.0f / (1.0f + expf(-s));
    }
}

extern "C" void kernel_launch(void* const* d_in, const int* in_sizes, int n_in,
                              void* d_out, int out_size, void* d_ws, size_t ws_size,
                              hipStream_t stream) {
    const float* x     = (const float*)d_in[0];
    const int*   ei    = (const int*)d_in[1];
    const int*   src   = ei;
    const int*   dst   = ei + NE;
    const int*   batch = (const int*)d_in[3];
    const float* Wl    = (const float*)d_in[4];
    const float* bl    = (const float*)d_in[5];
    const float* Wr    = (const float*)d_in[6];
    const float* gamma = (const float*)d_in[7];
    const float* beta  = (const float*)d_in[8];
    const float* fcw   = (const float*)d_in[9];
    const float* fcb   = (const float*)d_in[10];
    float* out = (float*)d_out;

    f16* hf0  = (f16*)d_ws;                       // [NN][128] fp16 (x converted)
    f16* hfA  = hf0 + (size_t)NN * HD;
    f16* hfB  = hfA + (size_t)NN * HD;
    f16* aggf = hfB + (size_t)NN * HD;
    f16* Wh   = aggf + (size_t)NN * HD;           // [128][256] fp16
    float* bias2 = (float*)(Wh + 128 * 256);      // 128
    // ---- contiguous zero zone (single memset) ----
    float* zero0    = bias2 + HD;
    float* statsRaw = zero0;                      // 3 layers x NREP x 256
    float* pooled   = statsRaw + 3 * NREP * 256;  // NG*HD
    int* bcnt  = (int*)(pooled + NG * HD);        // NB
    int* dhist = bcnt + NB;                       // 256
    size_t zero_bytes = (3 * NREP * 256 + NG * HD) * sizeof(float) + (NB + 256) * sizeof(int);
    // ---- rest ----
    int* rowptr  = dhist + 256;                   // NN+1
    int* perm    = rowptr + NN + 1;               // NE
    unsigned* staging = (unsigned*)(perm + NE);   // NE
    int* bbase   = (int*)(staging + NE);          // NB+1
    int* bcur    = bbase + NB + 1;                // NB
    int* gb      = bcur + NB;                     // NG+1
    int* norder  = gb + NG + 1;                   // NN
    int* dcur    = norder + NN;                   // 256

    hipMemsetAsync(zero0, 0, zero_bytes, stream);

    buckcnt_kernel<<<NCNT, 256, 0, stream>>>(dst, bcnt);
    buckscan_kernel<<<1, 256, 0, stream>>>(bcnt, bbase, bcur);
    buckscat_kernel<<<NCNT, 256, 0, stream>>>(src, dst, bcur, staging);
    buckbuild_kernel<<<NB, 256, 0, stream>>>(staging, bbase, rowptr, perm, dhist);
    dscan_kernel<<<1, 256, 0, stream>>>(dhist, dcur);
    place_kernel<<<(NN + 255) / 256, 256, 0, stream>>>(rowptr, dcur, norder);
    cvt_kernel<<<GATHB, 256, 0, stream>>>(x, hf0, batch, gb);

    const f16* hin = hf0;
    f16* houts[3] = {hfA, hfB, hfA};
    for (int l = 0; l < NL; ++l) {
        const float* stP = (l == 0) ? nullptr : (statsRaw + (l - 1) * NREP * 256);
        const float* gP  = gamma + (l == 0 ? 0 : (l - 1)) * HD;
        const float* bP  = beta + (l == 0 ? 0 : (l - 1)) * HD;
        gatherw_kernel<<<GATHB + 128, 256, 0, stream>>>(
            hin, rowptr, perm, norder, stP, gP, bP,
            Wl + l * HD * HD, Wr + l * HD * HD, bl + l * HD, Wh, bias2, aggf);
        mfma_gemm<<<(NN + 63) / 64, 256, 0, stream>>>(aggf, hin, Wh, bias2,
                                                      houts[l], statsRaw + l * NREP * 256);
        hin = houts[l];
    }
    pool2_kernel<<<NG * 8, 256, 0, stream>>>(hfA, gb, pooled);
    head_kernel<<<NG, 128, 0, stream>>>(pooled, gb, statsRaw + 2 * NREP * 256,
                                        gamma + 2 * HD, beta + 2 * HD, fcw, fcb, out);
}